// Round 5
// baseline (130.079 us; speedup 1.0000x reference)
//
#include <hip/hip_runtime.h>
#include <math.h>

// ---------------------------------------------------------------------------
// OBB CIoU loss, N independent box pairs -> scalar mean.
// R16: ILP probe. Evidence: R15 null with VGPR stuck at 32 (compiler not
// register-starved); wave lifetime ~12us vs ~1.4us VALU issue (issue
// interval ~17 cyc) -> waves stall ~88% despite in-thread ILP. Theory: the
// scheduler fails to overlap chains in the 1000-instr straight-line body.
// Probe: process TWO independent pairs per thread with u-innermost unrolling
// on EVERY statement -- source-adjacent interleaving doubles ILP everywhere
// (incl. the depth-10 Batcher sort). Per-pair instruction count unchanged.
//   latency-bound  -> dur 57 -> ~36-44us, VALUBusy -> 55-70%
//   issue-fat      -> dur flat -> next round: instruction diet.
// Carried from R14/R15: box1-frame vertex generation with the reference's
// flipped-u quirk (u in (-1,0)), bf16 payload slab + packed-uint key Batcher
// sort + LDS gather, diamond pseudo-angle, native sin/cos, atan-identity
// v-term, frcp divides, exact-reference semantics.
// ---------------------------------------------------------------------------

#define BLOCK 256
#define PAIRS 2
#define NV 16
#define LDS_STRIDE 17   // 16 dword slots + 1 pad (odd stride -> 2-way free)

typedef float v2f __attribute__((ext_vector_type(2)));

// --- compile-time Batcher odd-even mergesort network for n=16 ---
struct CEList {
    int n;
    unsigned char lo[128];
    unsigned char hi[128];
};

constexpr CEList make_ces16() {
    CEList L{};
    L.n = 0;
    for (int p = 1; p < NV; p <<= 1)
        for (int k = p; k >= 1; k >>= 1)
            for (int j = k % p; j + k < NV; j += 2 * k)
                for (int i = 0; i < k; i++) {
                    int lo = i + j, hi = i + j + k;
                    if (hi < NV && (lo / (2 * p)) == (hi / (2 * p))) {
                        L.lo[L.n] = (unsigned char)lo;
                        L.hi[L.n] = (unsigned char)hi;
                        L.n++;
                    }
                }
    return L;
}

constexpr CEList CES = make_ces16();

__device__ __forceinline__ float frcp(float x) {
    return __builtin_amdgcn_rcpf(x);
}

__device__ __forceinline__ v2f splat2(float x) {
    v2f r; r.x = x; r.y = x; return r;
}

// (du,dv) = rotate e into box2's axis coords.
__device__ __forceinline__ v2f rot_ds(v2f e, float cd, float sd) {
    v2f sw; sw.x = e.y; sw.y = -e.x;
    return e * splat2(cd) + sw * splat2(sd);
}

// Diamond pseudo-angle, no wrap: range [0,4), a cyclic shift of atan2 order.
__device__ __forceinline__ float angle_key(float x, float y) {
    float ax = fabsf(x), ay = fabsf(y);
    float den = ax + ay;
    float r = x * frcp(den);
    r = (den > 0.f) ? r : 0.f;
    return (y >= 0.f) ? (1.f - r) : (3.f + r);
}

// Pack two floats to bf16x2 with round-to-nearest (payload only; keys exact).
__device__ __forceinline__ unsigned int pack_bf2(float x, float y) {
    unsigned int bx = __float_as_uint(x) + 0x8000u;
    unsigned int by = __float_as_uint(y) + 0x8000u;
    return (by & 0xFFFF0000u) | (bx >> 16);
}

// atan(z) for z in [0,1]: degree-11 odd minimax, max err ~1.5e-5 rad.
__device__ __forceinline__ float atan01(float z) {
    float z2 = z * z;
    float p = -0.01172120f;
    p = p * z2 + 0.05265332f;
    p = p * z2 - 0.11643287f;
    p = p * z2 + 0.19354346f;
    p = p * z2 - 0.33262347f;
    p = p * z2 + 0.99997726f;
    return z * p;
}

__global__ __launch_bounds__(BLOCK, 4)
void obb_ciou_kernel(const float* __restrict__ pred,
                     const float* __restrict__ tgt,
                     const float* __restrict__ wgt,
                     float* __restrict__ out,
                     int N, float invN)
{
    const float MEPS = 1e-6f;           // MODE_EPS
    const float PIf  = 3.14159265358979323846f;
    const float TOLm = 1.f + 2e-6f;     // (1 + 2*tol) slab half-width scale

    __shared__ unsigned int slab[PAIRS * BLOCK * LDS_STRIDE];
    unsigned int* const mybp[2] = {
        slab + (int)threadIdx.x * LDS_STRIDE,
        slab + BLOCK * LDS_STRIDE + (int)threadIdx.x * LDS_STRIDE
    };

    int base = blockIdx.x * (BLOCK * PAIRS) + (int)threadIdx.x;

    // ---- loads (invalid lanes clamp to element 0, weight zeroed) ----
    float pcx[2], pcy[2], pw[2], ph[2], pa[2];
    float tcx[2], tcy[2], tw[2], th[2], ta[2];
    float wv[2];
    #pragma unroll
    for (int u = 0; u < 2; u++) {
        int i = base + u * BLOCK;
        bool ok = i < N;
        int ic = ok ? i : 0;
        wv[u] = ok ? wgt[ic] : 0.f;
        const float* p = pred + (size_t)ic * 5;
        const float* t = tgt  + (size_t)ic * 5;
        pcx[u] = p[0]; pcy[u] = p[1]; pw[u] = p[2]; ph[u] = p[3]; pa[u] = p[4];
        tcx[u] = t[0]; tcy[u] = t[1]; tw[u] = t[2]; th[u] = t[3]; ta[u] = t[4];
    }

    // ---- trig + frame ----
    float ca[2], sa[2], cb[2], sb[2];
    float hw1[2], hh1[2], hw2[2], hh2[2];
    float ddx[2], ddy[2], cd[2], sd[2];
    v2f c2[2], A[2], B[2], C0[2], C1[2], C2c[2], C3[2];
    #pragma unroll
    for (int u = 0; u < 2; u++) {
        ca[u] = __cosf(pa[u]); sa[u] = __sinf(pa[u]);
        cb[u] = __cosf(ta[u]); sb[u] = __sinf(ta[u]);
        hw1[u] = 0.5f * pw[u]; hh1[u] = 0.5f * ph[u];
        hw2[u] = 0.5f * tw[u]; hh2[u] = 0.5f * th[u];
        ddx[u] = tcx[u] - pcx[u]; ddy[u] = tcy[u] - pcy[u];
        v2f dd;  dd.x = ddx[u];  dd.y = ddy[u];
        v2f dds; dds.x = ddy[u]; dds.y = -ddx[u];
        c2[u] = dd * splat2(ca[u]) + dds * splat2(sa[u]);
        cd[u] = cb[u] * ca[u] + sb[u] * sa[u];
        sd[u] = sb[u] * ca[u] - cb[u] * sa[u];
        v2f axd2; axd2.x = cd[u];  axd2.y = sd[u];
        v2f bxd2; bxd2.x = -sd[u]; bxd2.y = cd[u];
        A[u] = splat2(hw2[u]) * axd2;
        B[u] = splat2(hh2[u]) * bxd2;
        v2f qpA = c2[u] + A[u], qmA = c2[u] - A[u];
        C0[u] = qpA - B[u]; C1[u] = qmA - B[u];
        C2c[u] = qmA + B[u]; C3[u] = qpA + B[u];
    }

    v2f  V[2][NV];
    bool msk[2][NV];

    // ---- corners1 (= (+-hw1,+-hh1), ring order) inside box2 -> slots 0..3
    {
        float exl[2], exh[2], eyl[2], eyh[2], lw2[2], lh2[2];
        #pragma unroll
        for (int u = 0; u < 2; u++) {
            exl[u] = -hw1[u] - c2[u].x; exh[u] = hw1[u] - c2[u].x;
            eyl[u] = -hh1[u] - c2[u].y; eyh[u] = hh1[u] - c2[u].y;
            lw2[u] = hw2[u] * TOLm; lh2[u] = hh2[u] * TOLm;
        }
        #pragma unroll
        for (int k = 0; k < 4; k++) {
            #pragma unroll
            for (int u = 0; u < 2; u++) {
                v2f e;
                e.x = (k == 0 || k == 3) ? exh[u] : exl[u];
                e.y = (k < 2) ? eyl[u] : eyh[u];
                v2f duv = rot_ds(e, cd[u], sd[u]);
                msk[u][k] = (fabsf(duv.x) < lw2[u]) && (fabsf(duv.y) < lh2[u]);
                V[u][k].x = (k == 0 || k == 3) ? hw1[u] : -hw1[u];
                V[u][k].y = (k < 2) ? -hh1[u] : hh1[u];
            }
        }
    }

    // ---- corners2 inside box1 (axis-aligned slab) -> slots 4..7
    #pragma unroll
    for (int u = 0; u < 2; u++) {
        float lw1 = hw1[u] * TOLm, lh1 = hh1[u] * TOLm;
        msk[u][4] = (fabsf(C0[u].x) < lw1) && (fabsf(C0[u].y) < lh1);
        V[u][4] = C0[u];
        msk[u][5] = (fabsf(C1[u].x) < lw1) && (fabsf(C1[u].y) < lh1);
        V[u][5] = C1[u];
        msk[u][6] = (fabsf(C2c[u].x) < lw1) && (fabsf(C2c[u].y) < lh1);
        V[u][6] = C2c[u];
        msk[u][7] = (fabsf(C3[u].x) < lw1) && (fabsf(C3[u].y) < lh1);
        V[u][7] = C3[u];
    }

    // ---- quirky edge crossings -> slots 8..15 (2 per box1 edge) ----
    {
        float Sx[2][4], Sy[2][4], Dxe[2][4], Dye[2][4], iDx[2][4], iDy[2][4];
        #pragma unroll
        for (int u = 0; u < 2; u++) {
            float twcd = A[u].x + A[u].x, twsd = A[u].y + A[u].y;   // 2A
            float thsd = -(B[u].x + B[u].x), thcd = B[u].y + B[u].y;// 2B=(-thsd,thcd)
            float rax = frcp(twcd), ray = frcp(twsd);
            float rbx = frcp(thsd), rby = frcp(thcd);
            Sx[u][0] = C0[u].x; Sx[u][1] = C1[u].x;
            Sx[u][2] = C2c[u].x; Sx[u][3] = C3[u].x;
            Sy[u][0] = C0[u].y; Sy[u][1] = C1[u].y;
            Sy[u][2] = C2c[u].y; Sy[u][3] = C3[u].y;
            Dxe[u][0] = -twcd; Dxe[u][1] = -thsd; Dxe[u][2] = twcd; Dxe[u][3] = thsd;
            Dye[u][0] = -twsd; Dye[u][1] = thcd;  Dye[u][2] = twsd; Dye[u][3] = -thcd;
            iDx[u][0] = -rax; iDx[u][1] = -rbx; iDx[u][2] = rax; iDx[u][3] = rbx;
            iDy[u][0] = -ray; iDy[u][1] = rby;  iDy[u][2] = ray; iDy[u][3] = -rby;
        }
        #pragma unroll
        for (int e1 = 0; e1 < 4; e1++) {
            // box1 ring: e0 bottom(y=-hh1), e1 left(x=-hw1),
            //            e2 top(y=+hh1),   e3 right(x=+hw1)
            const bool horiz = (e1 == 0) || (e1 == 2);
            float q[2][4]; bool qm[2][4];
            #pragma unroll
            for (int j = 0; j < 4; j++) {
                #pragma unroll
                for (int u = 0; u < 2; u++) {
                    float cc  = (e1 == 0) ? -hh1[u] : (e1 == 1) ? -hw1[u]
                              : (e1 == 2) ?  hh1[u] :  hw1[u];
                    float lim = horiz ? hw1[u] : hh1[u];
                    float uu = horiz ? (cc - Sy[u][j]) * iDy[u][j]
                                     : (cc - Sx[u][j]) * iDx[u][j];
                    float w = horiz ? fmaf(uu, Dxe[u][j], Sx[u][j])
                                    : fmaf(uu, Dye[u][j], Sy[u][j]);
                    // u in (-1,0): frame-exact image of reference's flipped-u
                    // mask; |w|<lim == t in (0,1); parallel -> inf/NaN reject.
                    qm[u][j] = (uu > -1.f) && (uu < 0.f) && (fabsf(w) < lim);
                    q[u][j] = w;
                }
            }
            #pragma unroll
            for (int u = 0; u < 2; u++) {
                float cc  = (e1 == 0) ? -hh1[u] : (e1 == 1) ? -hw1[u]
                          : (e1 == 2) ?  hh1[u] :  hw1[u];
                bool mfL = qm[u][0] || qm[u][1];
                float fL = qm[u][0] ? q[u][0] : q[u][1];
                bool msL = qm[u][0] && qm[u][1];
                bool mfR = qm[u][2] || qm[u][3];
                float fR = qm[u][2] ? q[u][2] : q[u][3];
                bool msR = qm[u][2] && qm[u][3];
                int s0 = 8 + 2 * e1, s1 = s0 + 1;
                float w0 = mfL ? fL : fR;
                msk[u][s0] = mfL || mfR;
                float t2v = msL ? q[u][1] : fR;
                float w1 = mfL ? t2v : q[u][3];
                msk[u][s1] = msL || (mfL && mfR) || msR;
                if (horiz) { V[u][s0].x = w0; V[u][s0].y = cc;
                             V[u][s1].x = w1; V[u][s1].y = cc; }
                else       { V[u][s0].x = cc; V[u][s0].y = w0;
                             V[u][s1].x = cc; V[u][s1].y = w1; }
            }
        }
    }

    // ---- centroid of valid verts ----
    v2f s2[2]; float cnt[2];
    #pragma unroll
    for (int u = 0; u < 2; u++) { s2[u] = splat2(0.f); cnt[u] = 0.f; }
    const v2f Z2 = splat2(0.f);
    #pragma unroll
    for (int k = 0; k < NV; k++) {
        #pragma unroll
        for (int u = 0; u < 2; u++) {
            s2[u]  += msk[u][k] ? V[u][k] : Z2;
            cnt[u] += msk[u][k] ? 1.f : 0.f;
        }
    }
    v2f cen[2];
    #pragma unroll
    for (int u = 0; u < 2; u++)
        cen[u] = s2[u] * splat2(frcp(fmaxf(cnt[u], 1.f)));

    // ---- relative coords -> LDS scatter (bf16x2) + packed key (key|slot) --
    unsigned int ku[2][NV];
    #pragma unroll
    for (int k = 0; k < NV; k++) {
        #pragma unroll
        for (int u = 0; u < 2; u++) {
            v2f R = V[u][k] - cen[u];
            mybp[u][k] = pack_bf2(R.x, R.y);
            float a = msk[u][k] ? angle_key(R.x, R.y) : 1e7f;
            ku[u][k] = (__float_as_uint(a) & 0xFFFFFFF0u) | (unsigned int)k;
        }
    }

    // ---- sort 16 packed keys (Batcher network, interleaved 2 pairs) ----
    #pragma unroll
    for (int c = 0; c < CES.n; c++) {
        const int lo = CES.lo[c], hi = CES.hi[c];
        #pragma unroll
        for (int u = 0; u < 2; u++) {
            unsigned int a = ku[u][lo], b = ku[u][hi];
            ku[u][lo] = a < b ? a : b;
            ku[u][hi] = a < b ? b : a;
        }
    }

    // ---- gather payload by sorted index; select-once; shoelace ring ----
    const unsigned int VALID_LIM = 0x49742400u;  // bits of 1e6f
    float sx[2][NV], sy[2][NV];
    {
        float gx[2][NV], gy[2][NV]; bool gv[2][NV];
        #pragma unroll
        for (int k = 0; k < NV; k++) {
            #pragma unroll
            for (int u = 0; u < 2; u++) {
                unsigned int pk = mybp[u][ku[u][k] & 15u];
                gx[u][k] = __uint_as_float(pk << 16);
                gy[u][k] = __uint_as_float(pk & 0xFFFF0000u);
                gv[u][k] = ku[u][k] < VALID_LIM;
            }
        }
        #pragma unroll
        for (int k = 0; k < NV; k++) {
            #pragma unroll
            for (int u = 0; u < 2; u++) {
                sx[u][k] = gv[u][k] ? gx[u][k] : gx[u][0];
                sy[u][k] = gv[u][k] ? gy[u][k] : gy[u][0];
            }
        }
    }
    float cross[2] = { 0.f, 0.f };
    #pragma unroll
    for (int k = 0; k < NV; k++) {
        int kn = (k + 1) & (NV - 1);     // constant after unroll
        #pragma unroll
        for (int u = 0; u < 2; u++)
            cross[u] += sx[u][k] * sy[u][kn] - sy[u][k] * sx[u][kn];
    }

    // ---- CIoU tail ----
    float loss = 0.f;
    #pragma unroll
    for (int u = 0; u < 2; u++) {
        float inter = fabsf(cross[u]) * 0.5f;
        float area1 = pw[u] * ph[u], area2 = tw[u] * th[u];
        float iou = inter * frcp(area1 + area2 - inter);
        iou = fminf(fmaxf(iou, 0.f), 1.f);

        float cA = fabsf(ca[u]), sA = fabsf(sa[u]);
        float cB = fabsf(cb[u]), sB = fabsf(sb[u]);
        float dw1 = (pw[u] * cA + ph[u] * sA) * 0.5f;
        float dh1 = (pw[u] * sA + ph[u] * cA) * 0.5f;
        float dw2 = (tw[u] * cB + th[u] * sB) * 0.5f;
        float dh2 = (tw[u] * sB + th[u] * cB) * 0.5f;
        float hp0 = pcx[u] - dw1, hp1 = pcy[u] - dh1;
        float hp2 = pcx[u] + dw1, hp3 = pcy[u] + dh1;
        float ht0 = tcx[u] - dw2, ht1 = tcy[u] - dh2;
        float ht2 = tcx[u] + dw2, ht3 = tcy[u] + dh2;

        float enw = fmaxf(fmaxf(hp2, ht2) - fminf(hp0, ht0), 0.f);
        float enh = fmaxf(fmaxf(hp3, ht3) - fminf(hp1, ht1), 0.f);
        float c2v = enw * enw + enh * enh + MEPS;
        float rho2 = ddx[u] * ddx[u] + ddy[u] * ddy[u];

        // v-term: atan(r1)-atan(r2) = atan((r1-r2)/(1+r1*r2)); dv squared.
        float factor = 4.f / (PIf * PIf);
        float r1 = tw[u] * frcp(th[u] + MEPS);
        float r2 = pw[u] * frcp(ph[u] + MEPS);
        float xd = (r1 - r2) * frcp(1.f + r1 * r2);
        float axd = fabsf(xd);
        bool  big = axd > 1.f;
        float z   = big ? frcp(axd) : axd;
        float at  = atan01(z);
        float dvv = big ? ((0.5f * PIf) - at) : at;   // |atan(xd)|
        float v_ = factor * dvv * dvv;
        float alpha = (iou > 0.5f) ? v_ * frcp(1.f - iou + v_ + MEPS) : 0.f;

        float rhoterm = fminf(fmaxf(rho2 * frcp(c2v), 0.f), 1.f);
        float ciou = iou - (rhoterm + alpha * v_);
        loss += (1.f - ciou) * wv[u];
    }

    // ---- reduction: wave shuffle -> LDS -> one atomic per block ----
    #pragma unroll
    for (int off = 32; off > 0; off >>= 1)
        loss += __shfl_down(loss, off, 64);

    __shared__ float red[BLOCK / 64];
    int wave = threadIdx.x >> 6;
    int lane = threadIdx.x & 63;
    if (lane == 0) red[wave] = loss;
    __syncthreads();
    if (threadIdx.x == 0) {
        float s = 0.f;
        #pragma unroll
        for (int w = 0; w < BLOCK / 64; w++) s += red[w];
        atomicAdd(out, s * invN);
    }
}

extern "C" void kernel_launch(void* const* d_in, const int* in_sizes, int n_in,
                              void* d_out, int out_size, void* d_ws, size_t ws_size,
                              hipStream_t stream) {
    const float* pred = (const float*)d_in[0];
    const float* tgt  = (const float*)d_in[1];
    const float* wgt  = (const float*)d_in[2];
    float* out = (float*)d_out;
    int N = in_sizes[2];  // weight element count == N boxes

    hipMemsetAsync(out, 0, sizeof(float) * (size_t)out_size, stream);

    int grid = (N + BLOCK * PAIRS - 1) / (BLOCK * PAIRS);
    obb_ciou_kernel<<<grid, BLOCK, 0, stream>>>(pred, tgt, wgt, out, N,
                                                1.f / (float)N);
}